// Round 7
// baseline (227.589 us; speedup 1.0000x reference)
//
#include <hip/hip_runtime.h>
#include <hip/hip_bf16.h>
#include <hip/hip_fp16.h>
#include <stdint.h>

typedef _Float16 f16;
typedef __attribute__((ext_vector_type(8))) _Float16 half8;
typedef __attribute__((ext_vector_type(4))) _Float16 half4;
typedef __attribute__((ext_vector_type(4))) float f32x4;

#define L_SEQ 8192
#define H_DIM 1024
#define P_DIM 512
#define NB 256          // scan blocks
#define TT 32           // scan block length (L/NB)

// async global->LDS, 16B per lane, wave-uniform LDS base + lane*16
#define GL16(gp, lp)                                                        \
  __builtin_amdgcn_global_load_lds(                                          \
      (const __attribute__((address_space(1))) void*)(gp),                   \
      (__attribute__((address_space(3))) void*)(lp), 16, 0, 0)

// ---------------- per-mode constants (f64 internally) ----------------
// cst layout (floats):
//   [0,512): lbar_re              [512,1024): lbar_im
//   [1024,1536): gamma_re         [1536,2048): gamma_im
//   [3072,3584): Re(lbar^32)      [3584,4096): Im(lbar^32)
//   [11264,12288): S[n]=2^e_p (n=p and 512+p)  — GEMM1 epilogue scale
//   [12288,12800): 2^-e_p — folded into W1 rows (fp16-denormal guard)
__global__ void k_consts(const float* __restrict__ lre, const float* __restrict__ lim,
                         const float* __restrict__ lstep, float* __restrict__ cst) {
  int p = threadIdx.x;  // 512
  double step = exp((double)lstep[p]);
  double ar = (double)lre[p] * step, ai = (double)lim[p] * step;
  double er = exp(ar);
  double lbr = er * cos(ai), lbi = er * sin(ai);
  double nr = lbr - 1.0, ni = lbi;
  double d = (double)lre[p] * (double)lre[p] + (double)lim[p] * (double)lim[p];
  double gr = (nr * (double)lre[p] + ni * (double)lim[p]) / d;
  double gi = (ni * (double)lre[p] - nr * (double)lim[p]) / d;
  cst[p] = (float)lbr; cst[512 + p] = (float)lbi;
  cst[1024 + p] = (float)gr; cst[1536 + p] = (float)gi;
  {
    double eT = exp(ar * 32.0);
    cst[3072 + p] = (float)(eT * cos(ai * 32.0));
    cst[3584 + p] = (float)(eT * sin(ai * 32.0));
  }
  // power-of-2 normalization: |gamma| ~ dt can be 1e-3 -> W1 entries ~2e-5,
  // below fp16 min-normal 6.1e-5 (MFMA flushes denormals). Scale rows to O(1e-2),
  // re-apply the exact 2^e in the f32 GEMM1 epilogue.
  double gm = fmax(fabs(gr), fabs(gi));
  int e = ilogb(gm) + 1;
  float sc = ldexpf(1.0f, e);
  cst[11264 + p] = sc;
  cst[11264 + 512 + p] = sc;
  cst[12288 + p] = ldexpf(1.0f, -e);
}

// fused prep: blocks [0,4096) W1-gen, [4096,8192) W2-gen, [8192,16384) u->f16 cvt
__global__ void k_prep(const float* __restrict__ B, const float* __restrict__ C,
                       const float* __restrict__ u, const float* __restrict__ cst,
                       f16* __restrict__ W1, f16* __restrict__ W2,
                       f16* __restrict__ uh) {
  int blk = blockIdx.x;
  if (blk < 4096) {
    int idx = blk * 256 + threadIdx.x;  // 1M
    int n = idx >> 10, k = idx & 1023;
    int p = n & 511;
    float b0 = B[(size_t)(p * 1024 + k) * 2];
    float b1 = B[(size_t)(p * 1024 + k) * 2 + 1];
    float gr = cst[1024 + p], gi = cst[1536 + p];
    float inv = cst[12288 + p];
    float re = (gr * b0 - gi * b1) * inv;
    float im = (gr * b1 + gi * b0) * inv;
    W1[idx] = (f16)((n < 512) ? re : im);
  } else if (blk < 8192) {
    int idx = (blk - 4096) * 256 + threadIdx.x;
    int h = idx >> 10, k = idx & 1023;
    float v = (k < 512) ? 2.0f * C[(size_t)(h * 512 + k) * 2]
                        : -2.0f * C[(size_t)(h * 512 + (k - 512)) * 2 + 1];
    W2[idx] = (f16)v;
  } else {
    int i = (blk - 8192) * 256 + threadIdx.x;  // 2M float4 over 8M floats
    float4 v = reinterpret_cast<const float4*>(u)[i];
    half4 h;
    h.x = (f16)v.x; h.y = (f16)v.y; h.z = (f16)v.z; h.w = (f16)v.w;
    reinterpret_cast<half4*>(uh)[i] = h;
  }
}

// ---------------- GEMM: C[MxN] = A[MxK] * Bm[NxK]^T, fp16 in ----------------
// M=8192, N=1024, K=1024. 128x128 tile, 4 waves (2x2), 16x16x32 MFMA, BK=64.
// T2 XOR-swizzle (both-sides): linear LDS dest, inverse-swizzled global source,
// swizzled ds_read -> registers hold true k-slices; bank-conflict-free reads.
// EPI=0: out f16 = acc * S[col].  EPI=1: out f32 = acc + D[col]*Uh[row][col].
template <int EPI>
__global__ __launch_bounds__(256) void k_gemm(const f16* __restrict__ A,
                                              const f16* __restrict__ Bm,
                                              float* __restrict__ CmF,
                                              f16* __restrict__ CmH,
                                              const float* __restrict__ D,
                                              const f16* __restrict__ Uh,
                                              const float* __restrict__ S) {
  __shared__ f16 As[128 * 64];
  __shared__ f16 Bs[128 * 64];
  const int tid = threadIdx.x;
  const int wave = tid >> 6, lane = tid & 63;
  const int bm = blockIdx.x >> 3, bn = blockIdx.x & 7;  // 64 x 8 tiles
  const int m0 = bm * 128, n0 = bn * 128;
  const int wr = (wave >> 1) * 64, wc = (wave & 1) * 64;
  const int lr = lane & 15, lg = lane >> 4;
  f32x4 acc[4][4] = {};

  // staging: 1024 16B-chunks per tile; chunk c covers row r=c>>3.
  // global col ELEM pre-swizzled: ((c&7)*8) ^ ((r&7)<<3)  (same 128B line)
  int srow[4], scol[4];
#pragma unroll
  for (int w = 0; w < 4; ++w) {
    int c = w * 256 + tid;
    srow[w] = c >> 3;
    scol[w] = ((c & 7) * 8) ^ ((srow[w] & 7) << 3);
  }

  for (int kt = 0; kt < 16; ++kt) {
    const int k0 = kt * 64;
#pragma unroll
    for (int w = 0; w < 4; ++w) {
      GL16(A + (size_t)(m0 + srow[w]) * 1024 + k0 + scol[w],
           (char*)As + (w * 256 + wave * 64) * 16);
      GL16(Bm + (size_t)(n0 + srow[w]) * 1024 + k0 + scol[w],
           (char*)Bs + (w * 256 + wave * 64) * 16);
    }
    __syncthreads();
    half8 af[2][4], bf[2][4];
#pragma unroll
    for (int m = 0; m < 4; ++m) {
      int ra = wr + m * 16 + lr;
      int sw = (ra & 7) << 4;
      af[0][m] = *(const half8*)((const char*)As + ra * 128 + ((lg * 16) ^ sw));
      af[1][m] = *(const half8*)((const char*)As + ra * 128 + ((64 + lg * 16) ^ sw));
    }
#pragma unroll
    for (int n = 0; n < 4; ++n) {
      int rb = wc + n * 16 + lr;
      int sw = (rb & 7) << 4;
      bf[0][n] = *(const half8*)((const char*)Bs + rb * 128 + ((lg * 16) ^ sw));
      bf[1][n] = *(const half8*)((const char*)Bs + rb * 128 + ((64 + lg * 16) ^ sw));
    }
#pragma unroll
    for (int h = 0; h < 2; ++h)
#pragma unroll
      for (int m = 0; m < 4; ++m)
#pragma unroll
        for (int n = 0; n < 4; ++n)
          acc[m][n] = __builtin_amdgcn_mfma_f32_16x16x32_f16(af[h][m], bf[h][n], acc[m][n], 0, 0, 0);
    __syncthreads();
  }

#pragma unroll
  for (int m = 0; m < 4; ++m)
#pragma unroll
    for (int n = 0; n < 4; ++n) {
      int row = m0 + wr + m * 16 + lg * 4;
      int col = n0 + wc + n * 16 + lr;
      float scale = (EPI == 0) ? S[col] : 0.0f;
#pragma unroll
      for (int j = 0; j < 4; ++j) {
        float v = acc[m][n][j];
        if (EPI) {
          v += D[col] * (float)Uh[(size_t)(row + j) * 1024 + col];
          CmF[(size_t)(row + j) * 1024 + col] = v;
        } else {
          CmH[(size_t)(row + j) * 1024 + col] = (f16)(v * scale);
        }
      }
    }
}

// ---------------- blocked scan ----------------
// Bu layout: (L, 1024) f16; col p = re, col 512+p = im
__global__ void k_scanA(const f16* __restrict__ Bu, const float* __restrict__ cst,
                        float* __restrict__ carry) {
  int p = threadIdx.x;
  int b = blockIdx.x;
  float lbr = cst[p], lbi = cst[512 + p];
  float xr = 0.f, xi = 0.f;
  const f16* row = Bu + (size_t)b * TT * 1024;
  for (int t = 0; t < TT; ++t) {
    float br = (float)row[t * 1024 + p], bi = (float)row[t * 1024 + 512 + p];
    float nxr = lbr * xr - lbi * xi + br;
    float nxi = lbr * xi + lbi * xr + bi;
    xr = nxr; xi = nxi;
  }
  carry[b * 1024 + p] = xr;
  carry[b * 1024 + 512 + p] = xi;
}

// scanC with fused carry-prefix: block b first computes its own prefix
// acc = sum_{j<b} lbar^{32(b-1-j)} carry_j via iterative acc = l32*acc + c_j
// (coalesced, L2-resident carry), then does the local recompute scan.
// Emits fp16 Xcat; last block writes final state per `tail` layout.
__global__ void k_scanC(const f16* __restrict__ Bu, const float* __restrict__ cst,
                        const float* __restrict__ carry, f16* __restrict__ X,
                        float* __restrict__ fin, int tail) {
  int p = threadIdx.x;
  int b = blockIdx.x;
  float l32r = cst[3072 + p], l32i = cst[3584 + p];
  float xr = 0.f, xi = 0.f;
  for (int j = 0; j < b; ++j) {
    float cr = carry[j * 1024 + p], ci = carry[j * 1024 + 512 + p];
    float nr = l32r * xr - l32i * xi + cr;
    float ni = l32r * xi + l32i * xr + ci;
    xr = nr; xi = ni;
  }
  float lbr = cst[p], lbi = cst[512 + p];
  const f16* row = Bu + (size_t)b * TT * 1024;
  f16* xrow = X + (size_t)b * TT * 1024;
  for (int t = 0; t < TT; ++t) {
    float br = (float)row[t * 1024 + p], bi = (float)row[t * 1024 + 512 + p];
    float nxr = lbr * xr - lbi * xi + br;
    float nxi = lbr * xi + lbi * xr + bi;
    xr = nxr; xi = nxi;
    xrow[t * 1024 + p] = (f16)xr;
    xrow[t * 1024 + 512 + p] = (f16)xi;
  }
  if (b == NB - 1) {
    if (tail >= 1024) {          // complex64 viewed as f32: interleaved re/im
      fin[2 * p] = xr;
      fin[2 * p + 1] = xi;
    } else if (tail >= 512) {    // complex -> f32 keeps real part only
      fin[p] = xr;
    }
  }
}

extern "C" void kernel_launch(void* const* d_in, const int* in_sizes, int n_in,
                              void* d_out, int out_size, void* d_ws, size_t ws_size,
                              hipStream_t stream) {
  const float* u    = (const float*)d_in[0];  // (L,H)
  const float* lre  = (const float*)d_in[1];  // (P,)
  const float* lim  = (const float*)d_in[2];  // (P,)
  const float* B    = (const float*)d_in[3];  // (P,H,2)
  const float* C    = (const float*)d_in[4];  // (H,P,2)
  const float* D    = (const float*)d_in[5];  // (H,)
  const float* lstp = (const float*)d_in[6];  // (P,)
  float* out = (float*)d_out;
  int tail = out_size - L_SEQ * H_DIM;

  char* ws = (char*)d_ws;
  float* cst   = (float*)(ws + 0);            // 64 KB
  f16* uh      = (f16*)(ws + 65536);          // 16 MB
  f16* W1      = (f16*)(ws + 16842752);       // 2 MB
  f16* W2      = (f16*)(ws + 18939904);       // 2 MB
  f16* Bu      = (f16*)(ws + 21037056);       // 16 MB
  f16* Xc      = (f16*)(ws + 37814272);       // 16 MB
  float* carry = (float*)(ws + 54591488);     // 1 MB

  k_consts<<<1, 512, 0, stream>>>(lre, lim, lstp, cst);
  k_prep<<<16384, 256, 0, stream>>>(B, C, u, cst, W1, W2, uh);
  k_gemm<0><<<512, 256, 0, stream>>>(uh, W1, nullptr, Bu, nullptr, nullptr, cst + 11264);
  k_scanA<<<NB, 512, 0, stream>>>(Bu, cst, carry);
  k_scanC<<<NB, 512, 0, stream>>>(Bu, cst, carry, Xc, out + (size_t)L_SEQ * H_DIM, tail);
  k_gemm<1><<<512, 256, 0, stream>>>(Xc, W2, out, nullptr, D, uh, nullptr);
}

// Round 9
// 177.856 us; speedup vs baseline: 1.2796x; 1.2796x over previous
//
#include <hip/hip_runtime.h>
#include <hip/hip_bf16.h>
#include <hip/hip_fp16.h>
#include <stdint.h>

typedef _Float16 f16;
typedef __attribute__((ext_vector_type(8))) _Float16 half8;
typedef __attribute__((ext_vector_type(4))) _Float16 half4;
typedef __attribute__((ext_vector_type(4))) float f32x4;

#define L_SEQ 8192
#define H_DIM 1024
#define P_DIM 512
#define NB 256          // scan blocks
#define TT 32           // scan block length (L/NB)

// async global->LDS, 16B per lane, wave-uniform LDS base + lane*16
#define GL16(gp, lp)                                                        \
  __builtin_amdgcn_global_load_lds(                                          \
      (const __attribute__((address_space(1))) void*)(gp),                   \
      (__attribute__((address_space(3))) void*)(lp), 16, 0, 0)

// ---------------- per-mode constants (f64 internally) ----------------
// cst layout (floats):
//   [0,512): lbar_re              [512,1024): lbar_im
//   [1024,1536): gamma_re         [1536,2048): gamma_im
//   [3072 + s*1024 + p]:       Re(lbar^(32*2^s)), s=0..7   (scanB Kogge-Stone)
//   [3072 + s*1024 + 512 + p]: Im(lbar^(32*2^s))
//   [11264,12288): S[n]=2^e_p for n=2p,2p+1 — GEMM1 epilogue scale (interleaved)
//   [12288,12800): 2^-e_p — folded into W1 rows (fp16-denormal guard)
__global__ void k_consts(const float* __restrict__ lre, const float* __restrict__ lim,
                         const float* __restrict__ lstep, float* __restrict__ cst) {
  int p = threadIdx.x;  // 512
  double step = exp((double)lstep[p]);
  double ar = (double)lre[p] * step, ai = (double)lim[p] * step;
  double er = exp(ar);
  double lbr = er * cos(ai), lbi = er * sin(ai);
  double nr = lbr - 1.0, ni = lbi;
  double d = (double)lre[p] * (double)lre[p] + (double)lim[p] * (double)lim[p];
  double gr = (nr * (double)lre[p] + ni * (double)lim[p]) / d;
  double gi = (ni * (double)lre[p] - nr * (double)lim[p]) / d;
  cst[p] = (float)lbr; cst[512 + p] = (float)lbi;
  cst[1024 + p] = (float)gr; cst[1536 + p] = (float)gi;
#pragma unroll
  for (int s = 0; s < 8; ++s) {
    double n = 32.0 * (double)(1 << s);
    double eT = exp(ar * n);
    cst[3072 + s * 1024 + p]       = (float)(eT * cos(ai * n));
    cst[3072 + s * 1024 + 512 + p] = (float)(eT * sin(ai * n));
  }
  // power-of-2 normalization: |gamma| ~ dt can be 1e-3 -> W1 entries ~2e-5,
  // below fp16 min-normal 6.1e-5 (MFMA flushes denormals). Scale rows to O(1e-2),
  // re-apply the exact 2^e in the f32 GEMM1 epilogue.
  double gm = fmax(fabs(gr), fabs(gi));
  int e = ilogb(gm) + 1;
  float sc = ldexpf(1.0f, e);
  cst[11264 + 2 * p] = sc;
  cst[11264 + 2 * p + 1] = sc;
  cst[12288 + p] = ldexpf(1.0f, -e);
}

// fused prep: blocks [0,4096) W1-gen, [4096,8192) W2-gen, [8192,16384) u->f16 cvt
// Interleaved mode layout: W1 row n: p=n>>1, n&1 ? Im : Re  (so Bu col 2p/2p+1 = re/im)
// W2 col k: p=k>>1, k&1 ? -2*C_im[h][p] : 2*C_re[h][p]      (consumes Xc interleaved)
__global__ void k_prep(const float* __restrict__ B, const float* __restrict__ C,
                       const float* __restrict__ u, const float* __restrict__ cst,
                       f16* __restrict__ W1, f16* __restrict__ W2,
                       f16* __restrict__ uh) {
  int blk = blockIdx.x;
  if (blk < 4096) {
    int idx = blk * 256 + threadIdx.x;  // 1M
    int n = idx >> 10, k = idx & 1023;
    int p = n >> 1;
    float b0 = B[(size_t)(p * 1024 + k) * 2];
    float b1 = B[(size_t)(p * 1024 + k) * 2 + 1];
    float gr = cst[1024 + p], gi = cst[1536 + p];
    float inv = cst[12288 + p];
    float re = (gr * b0 - gi * b1) * inv;
    float im = (gr * b1 + gi * b0) * inv;
    W1[idx] = (f16)((n & 1) ? im : re);
  } else if (blk < 8192) {
    int idx = (blk - 4096) * 256 + threadIdx.x;
    int h = idx >> 10, k = idx & 1023;
    int p = k >> 1;
    float v = (k & 1) ? -2.0f * C[(size_t)(h * 512 + p) * 2 + 1]
                      :  2.0f * C[(size_t)(h * 512 + p) * 2];
    W2[idx] = (f16)v;
  } else {
    int i = (blk - 8192) * 256 + threadIdx.x;  // 2M float4 over 8M floats
    float4 v = reinterpret_cast<const float4*>(u)[i];
    half4 h;
    h.x = (f16)v.x; h.y = (f16)v.y; h.z = (f16)v.z; h.w = (f16)v.w;
    reinterpret_cast<half4*>(uh)[i] = h;
  }
}

// ---------------- GEMM: C[MxN] = A[MxK] * Bm[NxK]^T, fp16 in ----------------
// M=8192, N=1024, K=1024. 128x128 tile, 4 waves (2x2), 16x16x32 MFMA, BK=64.
// T2 XOR-swizzle (both-sides): linear LDS dest, inverse-swizzled global source,
// swizzled ds_read -> registers hold true k-slices; bank-conflict-free reads.
// EPI=0: out f16 = acc * S[col].  EPI=1: out f32 = acc + D[col]*Uh[row][col].
template <int EPI>
__global__ __launch_bounds__(256) void k_gemm(const f16* __restrict__ A,
                                              const f16* __restrict__ Bm,
                                              float* __restrict__ CmF,
                                              f16* __restrict__ CmH,
                                              const float* __restrict__ D,
                                              const f16* __restrict__ Uh,
                                              const float* __restrict__ S) {
  __shared__ f16 As[128 * 64];
  __shared__ f16 Bs[128 * 64];
  const int tid = threadIdx.x;
  const int wave = tid >> 6, lane = tid & 63;
  const int bm = blockIdx.x >> 3, bn = blockIdx.x & 7;  // 64 x 8 tiles
  const int m0 = bm * 128, n0 = bn * 128;
  const int wr = (wave >> 1) * 64, wc = (wave & 1) * 64;
  const int lr = lane & 15, lg = lane >> 4;
  f32x4 acc[4][4] = {};

  // staging: 1024 16B-chunks per tile; chunk c covers row r=c>>3.
  // global col ELEM pre-swizzled: ((c&7)*8) ^ ((r&7)<<3)  (same 128B line)
  int srow[4], scol[4];
#pragma unroll
  for (int w = 0; w < 4; ++w) {
    int c = w * 256 + tid;
    srow[w] = c >> 3;
    scol[w] = ((c & 7) * 8) ^ ((srow[w] & 7) << 3);
  }

  for (int kt = 0; kt < 16; ++kt) {
    const int k0 = kt * 64;
#pragma unroll
    for (int w = 0; w < 4; ++w) {
      GL16(A + (size_t)(m0 + srow[w]) * 1024 + k0 + scol[w],
           (char*)As + (w * 256 + wave * 64) * 16);
      GL16(Bm + (size_t)(n0 + srow[w]) * 1024 + k0 + scol[w],
           (char*)Bs + (w * 256 + wave * 64) * 16);
    }
    __syncthreads();
    half8 af[2][4], bf[2][4];
#pragma unroll
    for (int m = 0; m < 4; ++m) {
      int ra = wr + m * 16 + lr;
      int sw = (ra & 7) << 4;
      af[0][m] = *(const half8*)((const char*)As + ra * 128 + ((lg * 16) ^ sw));
      af[1][m] = *(const half8*)((const char*)As + ra * 128 + ((64 + lg * 16) ^ sw));
    }
#pragma unroll
    for (int n = 0; n < 4; ++n) {
      int rb = wc + n * 16 + lr;
      int sw = (rb & 7) << 4;
      bf[0][n] = *(const half8*)((const char*)Bs + rb * 128 + ((lg * 16) ^ sw));
      bf[1][n] = *(const half8*)((const char*)Bs + rb * 128 + ((64 + lg * 16) ^ sw));
    }
#pragma unroll
    for (int h = 0; h < 2; ++h)
#pragma unroll
      for (int m = 0; m < 4; ++m)
#pragma unroll
        for (int n = 0; n < 4; ++n)
          acc[m][n] = __builtin_amdgcn_mfma_f32_16x16x32_f16(af[h][m], bf[h][n], acc[m][n], 0, 0, 0);
    __syncthreads();
  }

#pragma unroll
  for (int m = 0; m < 4; ++m)
#pragma unroll
    for (int n = 0; n < 4; ++n) {
      int row = m0 + wr + m * 16 + lg * 4;
      int col = n0 + wc + n * 16 + lr;
      float scale = (EPI == 0) ? S[col] : 0.0f;
#pragma unroll
      for (int j = 0; j < 4; ++j) {
        float v = acc[m][n][j];
        if (EPI) {
          v += D[col] * (float)Uh[(size_t)(row + j) * 1024 + col];
          CmF[(size_t)(row + j) * 1024 + col] = v;
        } else {
          CmH[(size_t)(row + j) * 1024 + col] = (f16)(v * scale);
        }
      }
    }
}

// ---------------- blocked scan ----------------
// Bu layout: (L, 1024) f16, col 2p = re(mode p), col 2p+1 = im -> u32 loads
__global__ void k_scanA(const f16* __restrict__ Bu, const float* __restrict__ cst,
                        float* __restrict__ carry) {
  int p = threadIdx.x;
  int b = blockIdx.x;
  float lbr = cst[p], lbi = cst[512 + p];
  float xr = 0.f, xi = 0.f;
  const uint32_t* row32 = (const uint32_t*)(Bu + (size_t)b * TT * 1024);
#pragma unroll
  for (int t = 0; t < TT; ++t) {
    union { uint32_t u; f16 h[2]; } cv;
    cv.u = row32[t * 512 + p];
    float br = (float)cv.h[0], bi = (float)cv.h[1];
    float nxr = lbr * xr - lbi * xi + br;
    float nxi = lbr * xi + lbi * xr + bi;
    xr = nxr; xi = nxi;
  }
  carry[b * 1024 + p] = xr;
  carry[b * 1024 + 512 + p] = xi;
}

// parallel carry-scan: one block per mode p (512 blocks), 256 threads (one per b).
// Kogge-Stone inclusive scan of carries with multiplier lbar^32; prefix[b] =
// inclusive[b-1] (state entering block b).
__global__ void k_scanB(const float* __restrict__ carry, const float* __restrict__ cst,
                        float* __restrict__ prefix) {
  __shared__ float sre[256], sim[256];
  int p = blockIdx.x;
  int b = threadIdx.x;
  float xr = carry[b * 1024 + p], xi = carry[b * 1024 + 512 + p];
  sre[b] = xr; sim[b] = xi;
  __syncthreads();
#pragma unroll
  for (int s = 0; s < 8; ++s) {
    float pr = cst[3072 + s * 1024 + p];
    float pi = cst[3072 + s * 1024 + 512 + p];
    int off = 1 << s;
    float ar = 0.f, ai = 0.f;
    if (b >= off) { ar = sre[b - off]; ai = sim[b - off]; }
    __syncthreads();
    xr += pr * ar - pi * ai;
    xi += pr * ai + pi * ar;
    sre[b] = xr; sim[b] = xi;
    __syncthreads();
  }
  float er = 0.f, ei = 0.f;
  if (b > 0) { er = sre[b - 1]; ei = sim[b - 1]; }
  prefix[b * 1024 + p] = er;
  prefix[b * 1024 + 512 + p] = ei;
}

// recompute scan with carry-in prefix; emit fp16 Xc interleaved (col 2p/2p+1).
// Last block writes final state; layout chosen by tail = out_size - L*H.
__global__ void k_scanC(const f16* __restrict__ Bu, const float* __restrict__ cst,
                        const float* __restrict__ prefix, f16* __restrict__ X,
                        float* __restrict__ fin, int tail) {
  int p = threadIdx.x;
  int b = blockIdx.x;
  float lbr = cst[p], lbi = cst[512 + p];
  float xr = prefix[b * 1024 + p], xi = prefix[b * 1024 + 512 + p];
  const uint32_t* row32 = (const uint32_t*)(Bu + (size_t)b * TT * 1024);
  uint32_t* xrow32 = (uint32_t*)(X + (size_t)b * TT * 1024);
#pragma unroll
  for (int t = 0; t < TT; ++t) {
    union { uint32_t u; f16 h[2]; } cv;
    cv.u = row32[t * 512 + p];
    float br = (float)cv.h[0], bi = (float)cv.h[1];
    float nxr = lbr * xr - lbi * xi + br;
    float nxi = lbr * xi + lbi * xr + bi;
    xr = nxr; xi = nxi;
    union { uint32_t u; f16 h[2]; } ov;
    ov.h[0] = (f16)xr; ov.h[1] = (f16)xi;
    xrow32[t * 512 + p] = ov.u;
  }
  if (b == NB - 1) {
    if (tail >= 1024) {          // complex64 viewed as f32: interleaved re/im
      fin[2 * p] = xr;
      fin[2 * p + 1] = xi;
    } else if (tail >= 512) {    // complex -> f32 keeps real part only
      fin[p] = xr;
    }
  }
}

extern "C" void kernel_launch(void* const* d_in, const int* in_sizes, int n_in,
                              void* d_out, int out_size, void* d_ws, size_t ws_size,
                              hipStream_t stream) {
  const float* u    = (const float*)d_in[0];  // (L,H)
  const float* lre  = (const float*)d_in[1];  // (P,)
  const float* lim  = (const float*)d_in[2];  // (P,)
  const float* B    = (const float*)d_in[3];  // (P,H,2)
  const float* C    = (const float*)d_in[4];  // (H,P,2)
  const float* D    = (const float*)d_in[5];  // (H,)
  const float* lstp = (const float*)d_in[6];  // (P,)
  float* out = (float*)d_out;
  int tail = out_size - L_SEQ * H_DIM;

  char* ws = (char*)d_ws;
  float* cst   = (float*)(ws + 0);            // 64 KB
  f16* uh      = (f16*)(ws + 65536);          // 16 MB
  f16* W1      = (f16*)(ws + 16842752);       // 2 MB
  f16* W2      = (f16*)(ws + 18939904);       // 2 MB
  f16* Bu      = (f16*)(ws + 21037056);       // 16 MB
  f16* Xc      = (f16*)(ws + 37814272);       // 16 MB
  float* carry = (float*)(ws + 54591488);     // 1 MB
  float* prefix= (float*)(ws + 55639040);     // 1 MB -> end 56686592

  k_consts<<<1, 512, 0, stream>>>(lre, lim, lstp, cst);
  k_prep<<<16384, 256, 0, stream>>>(B, C, u, cst, W1, W2, uh);
  k_gemm<0><<<512, 256, 0, stream>>>(uh, W1, nullptr, Bu, nullptr, nullptr, cst + 11264);
  k_scanA<<<NB, 512, 0, stream>>>(Bu, cst, carry);
  k_scanB<<<512, 256, 0, stream>>>(carry, cst, prefix);
  k_scanC<<<NB, 512, 0, stream>>>(Bu, cst, prefix, Xc, out + (size_t)L_SEQ * H_DIM, tail);
  k_gemm<1><<<512, 256, 0, stream>>>(Xc, W2, out, nullptr, D, uh, nullptr);
}

// Round 12
// 175.984 us; speedup vs baseline: 1.2932x; 1.0106x over previous
//
#include <hip/hip_runtime.h>
#include <hip/hip_bf16.h>
#include <hip/hip_fp16.h>
#include <stdint.h>

typedef _Float16 f16;
typedef __attribute__((ext_vector_type(8))) _Float16 half8;
typedef __attribute__((ext_vector_type(4))) _Float16 half4;
typedef __attribute__((ext_vector_type(4))) float f32x4;

#define L_SEQ 8192
#define H_DIM 1024
#define P_DIM 512
#define NB 256          // scan blocks
#define TT 32           // scan block length (L/NB)

// async global->LDS, 16B per lane, wave-uniform LDS base + lane*16
#define GL16(gp, lp)                                                        \
  __builtin_amdgcn_global_load_lds(                                          \
      (const __attribute__((address_space(1))) void*)(gp),                   \
      (__attribute__((address_space(3))) void*)(lp), 16, 0, 0)

// cst layout (floats):
//   [0,512): lbar_re              [512,1024): lbar_im
//   [3072 + s*1024 + p]:       Re(lbar^(32*2^s)), s=0..7   (scanB Kogge-Stone)
//   [3072 + s*1024 + 512 + p]: Im(lbar^(32*2^s))
//   [11264,12288): S[n]=2^e_p for n=2p,2p+1 — GEMM1 epilogue scale (interleaved)

// fused prep, 16392 blocks x 256:
//   [0,4096)      W1-gen (each block = single mode p; computes own f64 gamma)
//   [4096,8192)   W2-gen
//   [8192,16384)  u -> f16 cvt
//   [16384,16392) per-mode consts, 64 active threads/block (spread over 8 CUs)
// Interleaved mode layout: W1 row n: p=n>>1, n&1 ? Im : Re  (Bu col 2p/2p+1 = re/im)
// W2 col k: p=k>>1, k&1 ? -2*C_im[h][p] : 2*C_re[h][p]      (consumes Xc interleaved)
__global__ void k_prep(const float* __restrict__ B, const float* __restrict__ C,
                       const float* __restrict__ u, const float* __restrict__ lre,
                       const float* __restrict__ lim, const float* __restrict__ lstp,
                       float* __restrict__ cst, f16* __restrict__ W1,
                       f16* __restrict__ W2, f16* __restrict__ uh) {
  int blk = blockIdx.x;
  if (blk < 4096) {
    int idx = blk * 256 + threadIdx.x;  // 1M
    int n = idx >> 10, k = idx & 1023;
    int p = n >> 1;
    // inline f64 gamma for this block's single mode p (uniform work)
    double step = exp((double)lstp[p]);
    double ar = (double)lre[p] * step, ai = (double)lim[p] * step;
    double er = exp(ar);
    double lbr = er * cos(ai), lbi = er * sin(ai);
    double nr = lbr - 1.0, ni = lbi;
    double d = (double)lre[p] * (double)lre[p] + (double)lim[p] * (double)lim[p];
    double gr = (nr * (double)lre[p] + ni * (double)lim[p]) / d;
    double gi = (ni * (double)lre[p] - nr * (double)lim[p]) / d;
    // fp16-denormal guard: scale row to O(0.5), re-applied exactly in GEMM1 epilogue
    int e = ilogb(fmax(fabs(gr), fabs(gi))) + 1;
    float inv = ldexpf(1.0f, -e);
    float grf = (float)gr, gif = (float)gi;
    float b0 = B[(size_t)(p * 1024 + k) * 2];
    float b1 = B[(size_t)(p * 1024 + k) * 2 + 1];
    float re = (grf * b0 - gif * b1) * inv;
    float im = (grf * b1 + gif * b0) * inv;
    W1[idx] = (f16)((n & 1) ? im : re);
  } else if (blk < 8192) {
    int idx = (blk - 4096) * 256 + threadIdx.x;
    int h = idx >> 10, k = idx & 1023;
    int p = k >> 1;
    float v = (k & 1) ? -2.0f * C[(size_t)(h * 512 + p) * 2 + 1]
                      :  2.0f * C[(size_t)(h * 512 + p) * 2];
    W2[idx] = (f16)v;
  } else if (blk < 16384) {
    int i = (blk - 8192) * 256 + threadIdx.x;  // 2M float4 over 8M floats
    float4 v = reinterpret_cast<const float4*>(u)[i];
    half4 h;
    h.x = (f16)v.x; h.y = (f16)v.y; h.z = (f16)v.z; h.w = (f16)v.w;
    reinterpret_cast<half4*>(uh)[i] = h;
  } else {
    int t = threadIdx.x;
    if (t < 64) {
      int p = (blk - 16384) * 64 + t;  // 512 modes over 8 blocks
      double step = exp((double)lstp[p]);
      double ar = (double)lre[p] * step, ai = (double)lim[p] * step;
      double er = exp(ar);
      double lbr = er * cos(ai), lbi = er * sin(ai);
      cst[p] = (float)lbr; cst[512 + p] = (float)lbi;
      // lbar^32 by direct f64 eval, then 7 complex squarings (cheap, exact enough)
      double e32 = exp(ar * 32.0);
      double pr = e32 * cos(ai * 32.0), pi = e32 * sin(ai * 32.0);
#pragma unroll
      for (int s = 0; s < 8; ++s) {
        cst[3072 + s * 1024 + p]       = (float)pr;
        cst[3072 + s * 1024 + 512 + p] = (float)pi;
        double nr2 = pr * pr - pi * pi, ni2 = 2.0 * pr * pi;
        pr = nr2; pi = ni2;
      }
      // GEMM1 epilogue scale S = 2^e (must match W1 blocks' e: identical f64 sequence)
      double nr = lbr - 1.0, ni = lbi;
      double d = (double)lre[p] * (double)lre[p] + (double)lim[p] * (double)lim[p];
      double gr = (nr * (double)lre[p] + ni * (double)lim[p]) / d;
      double gi = (ni * (double)lre[p] - nr * (double)lim[p]) / d;
      int e = ilogb(fmax(fabs(gr), fabs(gi))) + 1;
      float sc = ldexpf(1.0f, e);
      cst[11264 + 2 * p] = sc;
      cst[11264 + 2 * p + 1] = sc;
    }
  }
}

// ---------------- GEMM: C[MxN] = A[MxK] * Bm[NxK]^T, fp16 in ----------------
// M=8192, N=1024, K=1024. 128x128 tile, 4 waves (2x2), 16x16x32 MFMA, BK=64.
// T2 XOR-swizzle (both-sides): linear LDS dest, inverse-swizzled global source,
// swizzled ds_read -> registers hold true k-slices; bank-conflict-free reads.
// EPI=0: out f16 = acc * S[col].  EPI=1: out f32 = acc + D[col]*Uh[row][col].
template <int EPI>
__global__ __launch_bounds__(256) void k_gemm(const f16* __restrict__ A,
                                              const f16* __restrict__ Bm,
                                              float* __restrict__ CmF,
                                              f16* __restrict__ CmH,
                                              const float* __restrict__ D,
                                              const f16* __restrict__ Uh,
                                              const float* __restrict__ S) {
  __shared__ f16 As[128 * 64];
  __shared__ f16 Bs[128 * 64];
  const int tid = threadIdx.x;
  const int wave = tid >> 6, lane = tid & 63;
  const int bm = blockIdx.x >> 3, bn = blockIdx.x & 7;  // 64 x 8 tiles
  const int m0 = bm * 128, n0 = bn * 128;
  const int wr = (wave >> 1) * 64, wc = (wave & 1) * 64;
  const int lr = lane & 15, lg = lane >> 4;
  f32x4 acc[4][4] = {};

  // staging: 1024 16B-chunks per tile; chunk c covers row r=c>>3.
  // global col ELEM pre-swizzled: ((c&7)*8) ^ ((r&7)<<3)  (same 128B line)
  int srow[4], scol[4];
#pragma unroll
  for (int w = 0; w < 4; ++w) {
    int c = w * 256 + tid;
    srow[w] = c >> 3;
    scol[w] = ((c & 7) * 8) ^ ((srow[w] & 7) << 3);
  }

  for (int kt = 0; kt < 16; ++kt) {
    const int k0 = kt * 64;
#pragma unroll
    for (int w = 0; w < 4; ++w) {
      GL16(A + (size_t)(m0 + srow[w]) * 1024 + k0 + scol[w],
           (char*)As + (w * 256 + wave * 64) * 16);
      GL16(Bm + (size_t)(n0 + srow[w]) * 1024 + k0 + scol[w],
           (char*)Bs + (w * 256 + wave * 64) * 16);
    }
    __syncthreads();
    half8 af[2][4], bf[2][4];
#pragma unroll
    for (int m = 0; m < 4; ++m) {
      int ra = wr + m * 16 + lr;
      int sw = (ra & 7) << 4;
      af[0][m] = *(const half8*)((const char*)As + ra * 128 + ((lg * 16) ^ sw));
      af[1][m] = *(const half8*)((const char*)As + ra * 128 + ((64 + lg * 16) ^ sw));
    }
#pragma unroll
    for (int n = 0; n < 4; ++n) {
      int rb = wc + n * 16 + lr;
      int sw = (rb & 7) << 4;
      bf[0][n] = *(const half8*)((const char*)Bs + rb * 128 + ((lg * 16) ^ sw));
      bf[1][n] = *(const half8*)((const char*)Bs + rb * 128 + ((64 + lg * 16) ^ sw));
    }
#pragma unroll
    for (int h = 0; h < 2; ++h)
#pragma unroll
      for (int m = 0; m < 4; ++m)
#pragma unroll
        for (int n = 0; n < 4; ++n)
          acc[m][n] = __builtin_amdgcn_mfma_f32_16x16x32_f16(af[h][m], bf[h][n], acc[m][n], 0, 0, 0);
    __syncthreads();
  }

#pragma unroll
  for (int m = 0; m < 4; ++m)
#pragma unroll
    for (int n = 0; n < 4; ++n) {
      int row = m0 + wr + m * 16 + lg * 4;
      int col = n0 + wc + n * 16 + lr;
      float scale = (EPI == 0) ? S[col] : 0.0f;
#pragma unroll
      for (int j = 0; j < 4; ++j) {
        float v = acc[m][n][j];
        if (EPI) {
          v += D[col] * (float)Uh[(size_t)(row + j) * 1024 + col];
          CmF[(size_t)(row + j) * 1024 + col] = v;
        } else {
          CmH[(size_t)(row + j) * 1024 + col] = (f16)(v * scale);
        }
      }
    }
}

// ---------------- blocked scan ----------------
// Bu layout: (L, 1024) f16, col 2p = re(mode p), col 2p+1 = im -> u32 loads
__global__ void k_scanA(const f16* __restrict__ Bu, const float* __restrict__ cst,
                        float* __restrict__ carry) {
  int p = threadIdx.x;
  int b = blockIdx.x;
  float lbr = cst[p], lbi = cst[512 + p];
  float xr = 0.f, xi = 0.f;
  const uint32_t* row32 = (const uint32_t*)(Bu + (size_t)b * TT * 1024);
#pragma unroll
  for (int t = 0; t < TT; ++t) {
    union { uint32_t u; f16 h[2]; } cv;
    cv.u = row32[t * 512 + p];
    float br = (float)cv.h[0], bi = (float)cv.h[1];
    float nxr = lbr * xr - lbi * xi + br;
    float nxi = lbr * xi + lbi * xr + bi;
    xr = nxr; xi = nxi;
  }
  carry[b * 1024 + p] = xr;
  carry[b * 1024 + 512 + p] = xi;
}

// parallel carry-scan: one block per mode p (512 blocks), 256 threads (one per b).
// Kogge-Stone inclusive scan of carries with multiplier lbar^32; prefix[b] =
// inclusive[b-1] (state entering block b).
__global__ void k_scanB(const float* __restrict__ carry, const float* __restrict__ cst,
                        float* __restrict__ prefix) {
  __shared__ float sre[256], sim[256];
  int p = blockIdx.x;
  int b = threadIdx.x;
  float xr = carry[b * 1024 + p], xi = carry[b * 1024 + 512 + p];
  sre[b] = xr; sim[b] = xi;
  __syncthreads();
#pragma unroll
  for (int s = 0; s < 8; ++s) {
    float pr = cst[3072 + s * 1024 + p];
    float pi = cst[3072 + s * 1024 + 512 + p];
    int off = 1 << s;
    float ar = 0.f, ai = 0.f;
    if (b >= off) { ar = sre[b - off]; ai = sim[b - off]; }
    __syncthreads();
    xr += pr * ar - pi * ai;
    xi += pr * ai + pi * ar;
    sre[b] = xr; sim[b] = xi;
    __syncthreads();
  }
  float er = 0.f, ei = 0.f;
  if (b > 0) { er = sre[b - 1]; ei = sim[b - 1]; }
  prefix[b * 1024 + p] = er;
  prefix[b * 1024 + 512 + p] = ei;
}

// recompute scan with carry-in prefix; emit fp16 Xc interleaved (col 2p/2p+1).
// Last block writes final state; layout chosen by tail = out_size - L*H.
__global__ void k_scanC(const f16* __restrict__ Bu, const float* __restrict__ cst,
                        const float* __restrict__ prefix, f16* __restrict__ X,
                        float* __restrict__ fin, int tail) {
  int p = threadIdx.x;
  int b = blockIdx.x;
  float lbr = cst[p], lbi = cst[512 + p];
  float xr = prefix[b * 1024 + p], xi = prefix[b * 1024 + 512 + p];
  const uint32_t* row32 = (const uint32_t*)(Bu + (size_t)b * TT * 1024);
  uint32_t* xrow32 = (uint32_t*)(X + (size_t)b * TT * 1024);
#pragma unroll
  for (int t = 0; t < TT; ++t) {
    union { uint32_t u; f16 h[2]; } cv;
    cv.u = row32[t * 512 + p];
    float br = (float)cv.h[0], bi = (float)cv.h[1];
    float nxr = lbr * xr - lbi * xi + br;
    float nxi = lbr * xi + lbi * xr + bi;
    xr = nxr; xi = nxi;
    union { uint32_t u; f16 h[2]; } ov;
    ov.h[0] = (f16)xr; ov.h[1] = (f16)xi;
    xrow32[t * 512 + p] = ov.u;
  }
  if (b == NB - 1) {
    if (tail >= 1024) {          // complex64 viewed as f32: interleaved re/im
      fin[2 * p] = xr;
      fin[2 * p + 1] = xi;
    } else if (tail >= 512) {    // complex -> f32 keeps real part only
      fin[p] = xr;
    }
  }
}

extern "C" void kernel_launch(void* const* d_in, const int* in_sizes, int n_in,
                              void* d_out, int out_size, void* d_ws, size_t ws_size,
                              hipStream_t stream) {
  const float* u    = (const float*)d_in[0];  // (L,H)
  const float* lre  = (const float*)d_in[1];  // (P,)
  const float* lim  = (const float*)d_in[2];  // (P,)
  const float* B    = (const float*)d_in[3];  // (P,H,2)
  const float* C    = (const float*)d_in[4];  // (H,P,2)
  const float* D    = (const float*)d_in[5];  // (H,)
  const float* lstp = (const float*)d_in[6];  // (P,)
  float* out = (float*)d_out;
  int tail = out_size - L_SEQ * H_DIM;

  char* ws = (char*)d_ws;
  float* cst   = (float*)(ws + 0);            // 64 KB
  f16* uh      = (f16*)(ws + 65536);          // 16 MB
  f16* W1      = (f16*)(ws + 16842752);       // 2 MB
  f16* W2      = (f16*)(ws + 18939904);       // 2 MB
  f16* Bu      = (f16*)(ws + 21037056);       // 16 MB
  f16* Xc      = (f16*)(ws + 37814272);       // 16 MB
  float* carry = (float*)(ws + 54591488);     // 1 MB
  float* prefix= (float*)(ws + 55639040);     // 1 MB -> end 56686592

  k_prep<<<16392, 256, 0, stream>>>(B, C, u, lre, lim, lstp, cst, W1, W2, uh);
  k_gemm<0><<<512, 256, 0, stream>>>(uh, W1, nullptr, Bu, nullptr, nullptr, cst + 11264);
  k_scanA<<<NB, 512, 0, stream>>>(Bu, cst, carry);
  k_scanB<<<512, 256, 0, stream>>>(carry, cst, prefix);
  k_scanC<<<NB, 512, 0, stream>>>(Bu, cst, prefix, Xc, out + (size_t)L_SEQ * H_DIM, tail);
  k_gemm<1><<<512, 256, 0, stream>>>(Xc, W2, out, nullptr, D, uh, nullptr);
}

// Round 13
// 166.917 us; speedup vs baseline: 1.3635x; 1.0543x over previous
//
#include <hip/hip_runtime.h>
#include <hip/hip_bf16.h>
#include <hip/hip_fp16.h>
#include <stdint.h>

typedef _Float16 f16;
typedef __attribute__((ext_vector_type(8))) _Float16 half8;
typedef __attribute__((ext_vector_type(4))) _Float16 half4;
typedef __attribute__((ext_vector_type(4))) float f32x4;

#define L_SEQ 8192
#define H_DIM 1024
#define P_DIM 512
#define NB 256          // scan blocks
#define TT 32           // scan block length (L/NB)

// async global->LDS, 16B per lane, wave-uniform LDS base + lane*16
#define GL16(gp, lp)                                                        \
  __builtin_amdgcn_global_load_lds(                                          \
      (const __attribute__((address_space(1))) void*)(gp),                   \
      (__attribute__((address_space(3))) void*)(lp), 16, 0, 0)

// cst layout (floats):
//   [0,512): lbar_re              [512,1024): lbar_im
//   [3072 + s*1024 + p]:       Re(lbar^(32*2^s)), s=0..7   (scanB Kogge-Stone)
//   [3072 + s*1024 + 512 + p]: Im(lbar^(32*2^s))
//   [11264,12288): S[n]=2^e_p for n=2p,2p+1 — GEMM1 epilogue scale (interleaved)

// fused prep, 16392 blocks x 256:
//   [0,4096)      W1-gen (block-uniform mode p; thread 0 computes f64 gamma, LDS bcast)
//   [4096,8192)   W2-gen
//   [8192,16384)  u -> f16 cvt
//   [16384,16392) per-mode consts, 64 active threads/block (spread over 8 CUs)
__global__ void k_prep(const float* __restrict__ B, const float* __restrict__ C,
                       const float* __restrict__ u, const float* __restrict__ lre,
                       const float* __restrict__ lim, const float* __restrict__ lstp,
                       float* __restrict__ cst, f16* __restrict__ W1,
                       f16* __restrict__ W2, f16* __restrict__ uh) {
  __shared__ float sg[3];
  int blk = blockIdx.x;
  if (blk < 4096) {
    int idx = blk * 256 + threadIdx.x;  // 1M
    int n = idx >> 10, k = idx & 1023;
    int p = n >> 1;                     // uniform across block (256 | 1024)
    if (threadIdx.x == 0) {
      double step = exp((double)lstp[p]);
      double ar = (double)lre[p] * step, ai = (double)lim[p] * step;
      double er = exp(ar);
      double lbr = er * cos(ai), lbi = er * sin(ai);
      double nr = lbr - 1.0, ni = lbi;
      double d = (double)lre[p] * (double)lre[p] + (double)lim[p] * (double)lim[p];
      double gr = (nr * (double)lre[p] + ni * (double)lim[p]) / d;
      double gi = (ni * (double)lre[p] - nr * (double)lim[p]) / d;
      // fp16-denormal guard exponent (must match consts path bitwise)
      int e = ilogb(fmax(fabs(gr), fabs(gi))) + 1;
      sg[0] = (float)gr; sg[1] = (float)gi; sg[2] = ldexpf(1.0f, -e);
    }
    __syncthreads();
    float grf = sg[0], gif = sg[1], inv = sg[2];
    float b0 = B[(size_t)(p * 1024 + k) * 2];
    float b1 = B[(size_t)(p * 1024 + k) * 2 + 1];
    float re = (grf * b0 - gif * b1) * inv;
    float im = (grf * b1 + gif * b0) * inv;
    W1[idx] = (f16)((n & 1) ? im : re);
  } else if (blk < 8192) {
    int idx = (blk - 4096) * 256 + threadIdx.x;
    int h = idx >> 10, k = idx & 1023;
    int p = k >> 1;
    float v = (k & 1) ? -2.0f * C[(size_t)(h * 512 + p) * 2 + 1]
                      :  2.0f * C[(size_t)(h * 512 + p) * 2];
    W2[idx] = (f16)v;
  } else if (blk < 16384) {
    int i = (blk - 8192) * 256 + threadIdx.x;  // 2M float4 over 8M floats
    float4 v = reinterpret_cast<const float4*>(u)[i];
    half4 h;
    h.x = (f16)v.x; h.y = (f16)v.y; h.z = (f16)v.z; h.w = (f16)v.w;
    reinterpret_cast<half4*>(uh)[i] = h;
  } else {
    int t = threadIdx.x;
    if (t < 64) {
      int p = (blk - 16384) * 64 + t;  // 512 modes over 8 blocks
      double step = exp((double)lstp[p]);
      double ar = (double)lre[p] * step, ai = (double)lim[p] * step;
      double er = exp(ar);
      double lbr = er * cos(ai), lbi = er * sin(ai);
      cst[p] = (float)lbr; cst[512 + p] = (float)lbi;
      // lbar^32 direct f64 eval, then 7 complex squarings
      double e32 = exp(ar * 32.0);
      double pr = e32 * cos(ai * 32.0), pi = e32 * sin(ai * 32.0);
#pragma unroll
      for (int s = 0; s < 8; ++s) {
        cst[3072 + s * 1024 + p]       = (float)pr;
        cst[3072 + s * 1024 + 512 + p] = (float)pi;
        double nr2 = pr * pr - pi * pi, ni2 = 2.0 * pr * pi;
        pr = nr2; pi = ni2;
      }
      // GEMM1 epilogue scale S = 2^e (identical f64 sequence as W1 path)
      double nr = lbr - 1.0, ni = lbi;
      double d = (double)lre[p] * (double)lre[p] + (double)lim[p] * (double)lim[p];
      double gr = (nr * (double)lre[p] + ni * (double)lim[p]) / d;
      double gi = (ni * (double)lre[p] - nr * (double)lim[p]) / d;
      int e = ilogb(fmax(fabs(gr), fabs(gi))) + 1;
      float sc = ldexpf(1.0f, e);
      cst[11264 + 2 * p] = sc;
      cst[11264 + 2 * p + 1] = sc;
    }
  }
}

// ---------------- GEMM: C[MxN] = A[MxK] * Bm[NxK]^T, fp16 in ----------------
// M=8192, N=1024, K=1024. 128x128 tile, 4 waves (2x2), 16x16x32 MFMA, BK=64.
// Double-buffered LDS prefetch (T3 minimum 2-phase, safe-barrier variant):
// STAGE(next) issued BEFORE compute(cur); __syncthreads() at iteration end
// drains the prefetch AFTER it had the whole MFMA phase to land.
// T2 XOR-swizzle (both-sides): linear LDS dest, inverse-swizzled global source,
// swizzled ds_read. T1 XCD swizzle: same-bm blocks colocate per XCD (A-panel L2 reuse).
// EPI=0: out f16 = acc * S[col].  EPI=1: out f32 = acc + D[col]*Uh[row][col].
template <int EPI>
__global__ __launch_bounds__(256) void k_gemm(const f16* __restrict__ A,
                                              const f16* __restrict__ Bm,
                                              float* __restrict__ CmF,
                                              f16* __restrict__ CmH,
                                              const float* __restrict__ D,
                                              const f16* __restrict__ Uh,
                                              const float* __restrict__ S) {
  __shared__ f16 As[2][128 * 64];
  __shared__ f16 Bs[2][128 * 64];
  const int tid = threadIdx.x;
  const int wave = tid >> 6, lane = tid & 63;
  // T1: bijective XCD swizzle for 512 blocks over 8 XCDs (64 each, same-bm adjacent)
  const int bid = blockIdx.x;
  const int swz = (bid & 7) * 64 + (bid >> 3);
  const int bm = swz >> 3, bn = swz & 7;  // 64 x 8 tiles
  const int m0 = bm * 128, n0 = bn * 128;
  const int wr = (wave >> 1) * 64, wc = (wave & 1) * 64;
  const int lr = lane & 15, lg = lane >> 4;
  f32x4 acc[4][4] = {};

  // staging: 1024 16B-chunks per tile; chunk c covers row r=c>>3.
  // global col ELEM pre-swizzled: ((c&7)*8) ^ ((r&7)<<3)  (same 128B line)
  int srow[4], scol[4];
#pragma unroll
  for (int w = 0; w < 4; ++w) {
    int c = w * 256 + tid;
    srow[w] = c >> 3;
    scol[w] = ((c & 7) * 8) ^ ((srow[w] & 7) << 3);
  }

#define STAGE(buf, kt)                                                        \
  {                                                                           \
    const int k0 = (kt) * 64;                                                 \
    _Pragma("unroll")                                                         \
    for (int w = 0; w < 4; ++w) {                                             \
      GL16(A + (size_t)(m0 + srow[w]) * 1024 + k0 + scol[w],                  \
           (char*)&As[buf][0] + (w * 256 + wave * 64) * 16);                  \
      GL16(Bm + (size_t)(n0 + srow[w]) * 1024 + k0 + scol[w],                 \
           (char*)&Bs[buf][0] + (w * 256 + wave * 64) * 16);                  \
    }                                                                         \
  }

  STAGE(0, 0);
  __syncthreads();

  for (int kt = 0; kt < 16; ++kt) {
    const int cur = kt & 1;
    if (kt < 15) STAGE(cur ^ 1, kt + 1);   // prefetch next tile during compute
    const char* pa = (const char*)&As[cur][0];
    const char* pb = (const char*)&Bs[cur][0];
    half8 af[2][4], bf[2][4];
#pragma unroll
    for (int m = 0; m < 4; ++m) {
      int ra = wr + m * 16 + lr;
      int sw = (ra & 7) << 4;
      af[0][m] = *(const half8*)(pa + ra * 128 + ((lg * 16) ^ sw));
      af[1][m] = *(const half8*)(pa + ra * 128 + ((64 + lg * 16) ^ sw));
    }
#pragma unroll
    for (int n = 0; n < 4; ++n) {
      int rb = wc + n * 16 + lr;
      int sw = (rb & 7) << 4;
      bf[0][n] = *(const half8*)(pb + rb * 128 + ((lg * 16) ^ sw));
      bf[1][n] = *(const half8*)(pb + rb * 128 + ((64 + lg * 16) ^ sw));
    }
#pragma unroll
    for (int h = 0; h < 2; ++h)
#pragma unroll
      for (int m = 0; m < 4; ++m)
#pragma unroll
        for (int n = 0; n < 4; ++n)
          acc[m][n] = __builtin_amdgcn_mfma_f32_16x16x32_f16(af[h][m], bf[h][n], acc[m][n], 0, 0, 0);
    __syncthreads();   // drains prefetch (landed during MFMA) + protects buffer swap
  }
#undef STAGE

#pragma unroll
  for (int m = 0; m < 4; ++m)
#pragma unroll
    for (int n = 0; n < 4; ++n) {
      int row = m0 + wr + m * 16 + lg * 4;
      int col = n0 + wc + n * 16 + lr;
      float scale = (EPI == 0) ? S[col] : 0.0f;
#pragma unroll
      for (int j = 0; j < 4; ++j) {
        float v = acc[m][n][j];
        if (EPI) {
          v += D[col] * (float)Uh[(size_t)(row + j) * 1024 + col];
          CmF[(size_t)(row + j) * 1024 + col] = v;
        } else {
          CmH[(size_t)(row + j) * 1024 + col] = (f16)(v * scale);
        }
      }
    }
}

// ---------------- blocked scan ----------------
// Bu layout: (L, 1024) f16, col 2p = re(mode p), col 2p+1 = im -> u32 loads
__global__ void k_scanA(const f16* __restrict__ Bu, const float* __restrict__ cst,
                        float* __restrict__ carry) {
  int p = threadIdx.x;
  int b = blockIdx.x;
  float lbr = cst[p], lbi = cst[512 + p];
  float xr = 0.f, xi = 0.f;
  const uint32_t* row32 = (const uint32_t*)(Bu + (size_t)b * TT * 1024);
#pragma unroll
  for (int t = 0; t < TT; ++t) {
    union { uint32_t u; f16 h[2]; } cv;
    cv.u = row32[t * 512 + p];
    float br = (float)cv.h[0], bi = (float)cv.h[1];
    float nxr = lbr * xr - lbi * xi + br;
    float nxi = lbr * xi + lbi * xr + bi;
    xr = nxr; xi = nxi;
  }
  carry[b * 1024 + p] = xr;
  carry[b * 1024 + 512 + p] = xi;
}

// parallel carry-scan: one block per mode p (512 blocks), 256 threads (one per b).
// Kogge-Stone inclusive scan of carries with multiplier lbar^32; prefix[b] =
// inclusive[b-1] (state entering block b).
__global__ void k_scanB(const float* __restrict__ carry, const float* __restrict__ cst,
                        float* __restrict__ prefix) {
  __shared__ float sre[256], sim[256];
  int p = blockIdx.x;
  int b = threadIdx.x;
  float xr = carry[b * 1024 + p], xi = carry[b * 1024 + 512 + p];
  sre[b] = xr; sim[b] = xi;
  __syncthreads();
#pragma unroll
  for (int s = 0; s < 8; ++s) {
    float pr = cst[3072 + s * 1024 + p];
    float pi = cst[3072 + s * 1024 + 512 + p];
    int off = 1 << s;
    float ar = 0.f, ai = 0.f;
    if (b >= off) { ar = sre[b - off]; ai = sim[b - off]; }
    __syncthreads();
    xr += pr * ar - pi * ai;
    xi += pr * ai + pi * ar;
    sre[b] = xr; sim[b] = xi;
    __syncthreads();
  }
  float er = 0.f, ei = 0.f;
  if (b > 0) { er = sre[b - 1]; ei = sim[b - 1]; }
  prefix[b * 1024 + p] = er;
  prefix[b * 1024 + 512 + p] = ei;
}

// recompute scan with carry-in prefix; emit fp16 Xc interleaved (col 2p/2p+1).
// Last block writes final state; layout chosen by tail = out_size - L*H.
__global__ void k_scanC(const f16* __restrict__ Bu, const float* __restrict__ cst,
                        const float* __restrict__ prefix, f16* __restrict__ X,
                        float* __restrict__ fin, int tail) {
  int p = threadIdx.x;
  int b = blockIdx.x;
  float lbr = cst[p], lbi = cst[512 + p];
  float xr = prefix[b * 1024 + p], xi = prefix[b * 1024 + 512 + p];
  const uint32_t* row32 = (const uint32_t*)(Bu + (size_t)b * TT * 1024);
  uint32_t* xrow32 = (uint32_t*)(X + (size_t)b * TT * 1024);
#pragma unroll
  for (int t = 0; t < TT; ++t) {
    union { uint32_t u; f16 h[2]; } cv;
    cv.u = row32[t * 512 + p];
    float br = (float)cv.h[0], bi = (float)cv.h[1];
    float nxr = lbr * xr - lbi * xi + br;
    float nxi = lbr * xi + lbi * xr + bi;
    xr = nxr; xi = nxi;
    union { uint32_t u; f16 h[2]; } ov;
    ov.h[0] = (f16)xr; ov.h[1] = (f16)xi;
    xrow32[t * 512 + p] = ov.u;
  }
  if (b == NB - 1) {
    if (tail >= 1024) {          // complex64 viewed as f32: interleaved re/im
      fin[2 * p] = xr;
      fin[2 * p + 1] = xi;
    } else if (tail >= 512) {    // complex -> f32 keeps real part only
      fin[p] = xr;
    }
  }
}

extern "C" void kernel_launch(void* const* d_in, const int* in_sizes, int n_in,
                              void* d_out, int out_size, void* d_ws, size_t ws_size,
                              hipStream_t stream) {
  const float* u    = (const float*)d_in[0];  // (L,H)
  const float* lre  = (const float*)d_in[1];  // (P,)
  const float* lim  = (const float*)d_in[2];  // (P,)
  const float* B    = (const float*)d_in[3];  // (P,H,2)
  const float* C    = (const float*)d_in[4];  // (H,P,2)
  const float* D    = (const float*)d_in[5];  // (H,)
  const float* lstp = (const float*)d_in[6];  // (P,)
  float* out = (float*)d_out;
  int tail = out_size - L_SEQ * H_DIM;

  char* ws = (char*)d_ws;
  float* cst   = (float*)(ws + 0);            // 64 KB
  f16* uh      = (f16*)(ws + 65536);          // 16 MB
  f16* W1      = (f16*)(ws + 16842752);       // 2 MB
  f16* W2      = (f16*)(ws + 18939904);       // 2 MB
  f16* Bu      = (f16*)(ws + 21037056);       // 16 MB
  f16* Xc      = (f16*)(ws + 37814272);       // 16 MB
  float* carry = (float*)(ws + 54591488);     // 1 MB
  float* prefix= (float*)(ws + 55639040);     // 1 MB -> end 56686592

  k_prep<<<16392, 256, 0, stream>>>(B, C, u, lre, lim, lstp, cst, W1, W2, uh);
  k_gemm<0><<<512, 256, 0, stream>>>(uh, W1, nullptr, Bu, nullptr, nullptr, cst + 11264);
  k_scanA<<<NB, 512, 0, stream>>>(Bu, cst, carry);
  k_scanB<<<512, 256, 0, stream>>>(carry, cst, prefix);
  k_scanC<<<NB, 512, 0, stream>>>(Bu, cst, prefix, Xc, out + (size_t)L_SEQ * H_DIM, tail);
  k_gemm<1><<<512, 256, 0, stream>>>(Xc, W2, out, nullptr, D, uh, nullptr);
}